// Round 11
// baseline (156.904 us; speedup 1.0000x reference)
//
#include <hip/hip_runtime.h>
#include <math.h>

// Problem constants
#define TT 16384   // tokens
#define HH 2048    // hidden
#define EE 64      // experts
#define KK 8       // top_k

#define TB 16          // tokens per block (one MFMA M-tile)
#define HC 64          // h per chunk (2 MFMA k-steps)
#define NCH (HH / HC)  // 32 chunks
#define TOPC 10        // fp32 candidate count for fixup
#define MARGIN 2.5e-5f // selection-score gap below which we fp64-verify

// Output layout (flat float32):
// probs [TT][KK] | indices [TT][KK] | map [TT][EE] | aux scalar
#define IDX_OFF ((size_t)TT * KK)
#define MAP_OFF ((size_t)2 * TT * KK)
#define AUX_OFF ((size_t)2 * TT * KK + (size_t)TT * EE)

// d_ws layout (bf16 shorts): hi plane then lo plane, each WSPLANE shorts.
// Fragment-native: [m (k/32)][kq][e][8 j] -> element (e, k=m*32+kq*8+j)
// at  m*2048 + kq*512 + e*8 + j.  (R10-validated.)
#define WSPLANE 131072

typedef short bf16x8 __attribute__((ext_vector_type(8)));
typedef float f32x4  __attribute__((ext_vector_type(4)));

__device__ __forceinline__ unsigned short f2bf(float x) {   // RNE fp32->bf16
    unsigned int u = __float_as_uint(x);
    u += 0x7FFFu + ((u >> 16) & 1u);
    return (unsigned short)(u >> 16);
}
__device__ __forceinline__ float bf2f(unsigned short b) {
    return __uint_as_float(((unsigned int)b) << 16);
}
__device__ __forceinline__ void cvt4(const float4 v, ushort4* hi, ushort4* lo) {
    unsigned short h0 = f2bf(v.x), h1 = f2bf(v.y),
                   h2 = f2bf(v.z), h3 = f2bf(v.w);
    *hi = make_ushort4(h0, h1, h2, h3);
    *lo = make_ushort4(f2bf(v.x - bf2f(h0)), f2bf(v.y - bf2f(h1)),
                       f2bf(v.z - bf2f(h2)), f2bf(v.w - bf2f(h3)));
}
// 8 consecutive fp32 -> hi/lo bf16x8 fragments, all in registers
__device__ __forceinline__ void cvt8(const float4 a, const float4 b,
                                     bf16x8* hi, bf16x8* lo) {
    const float v[8] = {a.x, a.y, a.z, a.w, b.x, b.y, b.z, b.w};
    bf16x8 h, l;
    #pragma unroll
    for (int i = 0; i < 8; ++i) {
        unsigned short hb = f2bf(v[i]);
        h[i] = (short)hb;
        l[i] = (short)f2bf(v[i] - bf2f(hb));
    }
    *hi = h; *lo = l;
}

// ---- prep: gate_w fp32 -> bf16 hi/lo planes in fragment-native layout ----
__global__ __launch_bounds__(256)
void prep_kernel(const float* __restrict__ gw, unsigned short* __restrict__ ws)
{
    const int gid = blockIdx.x * 256 + threadIdx.x;   // 0..32767 float4 slots
    const int e  = gid >> 9;          // 512 float4 per expert row
    const int k  = (gid & 511) * 4;
    float4 v = *(const float4*)(gw + (size_t)e * HH + k);
    ushort4 hi, lo;
    cvt4(v, &hi, &lo);
    const int off = (k >> 5) * 2048 + ((k >> 3) & 3) * 512 + e * 8 + (k & 7);
    *(ushort4*)(ws + off)           = hi;
    *(ushort4*)(ws + WSPLANE + off) = lo;
}

// ---- main: barrier-free hot loop; A-frags direct from global, in-reg cvt ----
__global__ __launch_bounds__(256, 4)
void router_kernel(const float* __restrict__ hidden,
                   const float* __restrict__ gate_w,
                   const float* __restrict__ bias,
                   const unsigned short* __restrict__ wsbuf,
                   float* __restrict__ out)
{
    __shared__ __align__(16) float lg[16 * 68 + 8];   // logit exchange only

    const int tid  = threadIdx.x;
    const int tok0 = blockIdx.x * TB;

    // fragment coords (R9/R10-validated conventions)
    const int lane = tid & 63;
    const int e0   = (tid >> 6) * 16;   // wave's expert tile
    const int rx   = lane & 15;
    const int kq   = lane >> 4;

    // A-frag global base: row rx, k-offset kq*8 (two float4 = 8 floats/frag)
    const float* hgp = hidden + (size_t)(tok0 + rx) * HH + kq * 8;
    // B-frag base in ws (fragment-native)
    const unsigned short* bBase = wsbuf + kq * 512 + (e0 + rx) * 8;

    f32x4 acc = {0.f, 0.f, 0.f, 0.f};

    #pragma unroll 2
    for (int c = 0; c < NCH; ++c) {
        // H direct loads: k-step 0 and 1 of chunk c (128-B coalesced rows)
        const float* hp = hgp + c * HC;
        float4 h0 = *(const float4*)(hp);
        float4 h1 = *(const float4*)(hp + 4);
        float4 h2 = *(const float4*)(hp + 32);
        float4 h3 = *(const float4*)(hp + 36);
        // B frags from L2-resident ws
        const unsigned short* bp = bBase + (size_t)(2 * c) * 2048;
        bf16x8 Bh0 = *(const bf16x8*)(bp);
        bf16x8 Bl0 = *(const bf16x8*)(bp + WSPLANE);
        bf16x8 Bh1 = *(const bf16x8*)(bp + 2048);
        bf16x8 Bl1 = *(const bf16x8*)(bp + 2048 + WSPLANE);
        // in-register fp32 -> bf16 hi/lo
        bf16x8 Ah0, Al0, Ah1, Al1;
        cvt8(h0, h1, &Ah0, &Al0);
        cvt8(h2, h3, &Ah1, &Al1);
        // bf16x3 MFMA
        acc = __builtin_amdgcn_mfma_f32_16x16x32_bf16(Ah0, Bl0, acc, 0, 0, 0);
        acc = __builtin_amdgcn_mfma_f32_16x16x32_bf16(Al0, Bh0, acc, 0, 0, 0);
        acc = __builtin_amdgcn_mfma_f32_16x16x32_bf16(Ah0, Bh0, acc, 0, 0, 0);
        acc = __builtin_amdgcn_mfma_f32_16x16x32_bf16(Ah1, Bl1, acc, 0, 0, 0);
        acc = __builtin_amdgcn_mfma_f32_16x16x32_bf16(Al1, Bh1, acc, 0, 0, 0);
        acc = __builtin_amdgcn_mfma_f32_16x16x32_bf16(Ah1, Bh1, acc, 0, 0, 0);
    }

    // ---- logits to LDS: row = token = 4*kq + r, col = expert = e0 + rx ----
    #pragma unroll
    for (int r = 0; r < 4; ++r)
        lg[(4 * kq + r) * 68 + e0 + rx] = acc[r];
    __syncthreads();

    // ---- epilogue: 16 lanes per token (R9/R10-validated machinery) ----
    const int t   = tid >> 4;   // 0..15
    const int q   = tid & 15;   // lane owns experts q + 16i, i=0..3
    const int tok = tok0 + t;

    float lv[4];
    #pragma unroll
    for (int i = 0; i < 4; ++i) lv[i] = lg[t * 68 + q + 16 * i];

    float mx = lv[0];
    #pragma unroll
    for (int i = 1; i < 4; ++i) mx = fmaxf(mx, lv[i]);
    #pragma unroll
    for (int sh = 1; sh < 16; sh <<= 1) mx = fmaxf(mx, __shfl_xor(mx, sh, 64));

    float ex[4], psum = 0.0f;
    #pragma unroll
    for (int i = 0; i < 4; ++i) { ex[i] = expf(lv[i] - mx); psum += ex[i]; }
    #pragma unroll
    for (int sh = 1; sh < 16; sh <<= 1) psum += __shfl_xor(psum, sh, 64);
    const float inv = 1.0f / psum;

    float pr[4], selv[4];
    #pragma unroll
    for (int i = 0; i < 4; ++i) {
        pr[i]   = ex[i] * inv;
        selv[i] = pr[i] + bias[q + 16 * i];
    }

    // top-10 candidates (fp32), strict-> with lowest-index tie-break
    float ws_[TOPC], wp[TOPC];
    int   wi[TOPC];
    #pragma unroll
    for (int k = 0; k < TOPC; ++k) {
        float bs = selv[0], bp = pr[0];
        int bi = q;
        #pragma unroll
        for (int i = 1; i < 4; ++i)
            if (selv[i] > bs) { bs = selv[i]; bp = pr[i]; bi = q + 16 * i; }
        #pragma unroll
        for (int sh = 1; sh < 16; sh <<= 1) {
            float os = __shfl_xor(bs, sh, 64);
            float op = __shfl_xor(bp, sh, 64);
            int   ob = __shfl_xor(bi, sh, 64);
            if (os > bs || (os == bs && ob < bi)) { bs = os; bp = op; bi = ob; }
        }
        ws_[k] = bs; wp[k] = bp; wi[k] = bi;
        #pragma unroll
        for (int i = 0; i < 4; ++i)
            if (q + 16 * i == bi) selv[i] = -INFINITY;
    }

    // flag: any adjacent gap among ranks 1..9 too small to trust bf16x3
    bool flag = false;
    #pragma unroll
    for (int k = 0; k < 8; ++k)
        flag = flag || (ws_[k] - ws_[k + 1] < MARGIN);

    if (flag) {   // uniform across the 16-lane token group
        const float* hrow = hidden + (size_t)tok * HH;
        const float* wr_[TOPC];
        #pragma unroll
        for (int k = 0; k < TOPC; ++k) wr_[k] = gate_w + (size_t)wi[k] * HH;

        double l64[TOPC];
        #pragma unroll
        for (int k = 0; k < TOPC; ++k) l64[k] = 0.0;

        for (int m = 0; m < 32; ++m) {
            float4 h4 = *(const float4*)(hrow + m * 64 + 4 * q);
            double h0 = h4.x, h1 = h4.y, h2 = h4.z, h3 = h4.w;
            #pragma unroll
            for (int k = 0; k < TOPC; ++k) {
                float4 w4 = *(const float4*)(wr_[k] + m * 64 + 4 * q);
                l64[k] = fma(h0, (double)w4.x, l64[k]);
                l64[k] = fma(h1, (double)w4.y, l64[k]);
                l64[k] = fma(h2, (double)w4.z, l64[k]);
                l64[k] = fma(h3, (double)w4.w, l64[k]);
            }
        }
        #pragma unroll
        for (int k = 0; k < TOPC; ++k)
            #pragma unroll
            for (int sh = 1; sh < 16; sh <<= 1)
                l64[k] += __shfl_xor(l64[k], sh, 64);

        // exact-rank selection scores (common positive rescale; bias exact)
        double s64[TOPC];
        #pragma unroll
        for (int k = 0; k < TOPC; ++k)
            s64[k] = exp(l64[k] - (double)mx) * (double)inv + (double)bias[wi[k]];

        // order first 8 by (score desc, idx asc) - static indices only
        #pragma unroll
        for (int a = 0; a < 8; ++a) {
            #pragma unroll
            for (int b = a + 1; b < TOPC; ++b) {
                bool sw = (s64[b] > s64[a]) ||
                          (s64[b] == s64[a] && wi[b] < wi[a]);
                if (sw) {
                    double td = s64[a]; s64[a] = s64[b]; s64[b] = td;
                    int    ti = wi[a];  wi[a]  = wi[b];  wi[b]  = ti;
                    float  tp = wp[a];  wp[a]  = wp[b];  wp[b]  = tp;
                }
            }
        }
    }

    // ---- common write-out (wi/wp[0..7] final) ----
    int oi = wi[0];
    float opf = wp[0];
    #pragma unroll
    for (int k = 1; k < 8; ++k)
        if (q == k) { oi = wi[k]; opf = wp[k]; }

    float ps = 0.0f;
    #pragma unroll
    for (int k = 0; k < 8; ++k) ps += wp[k];
    const float rinv = 1.0f / (ps + 1e-9f);

    if (q < KK) {
        out[(size_t)tok * KK + q]           = opf * rinv;
        out[IDX_OFF + (size_t)tok * KK + q] = (float)oi;
    }

    unsigned long long mk = 0ull;
    #pragma unroll
    for (int k = 0; k < 8; ++k) mk |= (1ull << wi[k]);

    {
        float4 a;
        a.x = ((mk >> (4 * q + 0)) & 1ull) ? 1.0f : 0.0f;
        a.y = ((mk >> (4 * q + 1)) & 1ull) ? 1.0f : 0.0f;
        a.z = ((mk >> (4 * q + 2)) & 1ull) ? 1.0f : 0.0f;
        a.w = ((mk >> (4 * q + 3)) & 1ull) ? 1.0f : 0.0f;
        *(float4*)(out + MAP_OFF + (size_t)tok * EE + 4 * q) = a;
    }

    if (blockIdx.x == 0 && tid == 0) out[AUX_OFF] = 0.0f;
}

extern "C" void kernel_launch(void* const* d_in, const int* in_sizes, int n_in,
                              void* d_out, int out_size, void* d_ws, size_t ws_size,
                              hipStream_t stream) {
    const float* hidden = (const float*)d_in[0];  // [16384, 2048] f32
    const float* gate_w = (const float*)d_in[1];  // [64, 2048] f32
    const float* bias   = (const float*)d_in[2];  // [64] f32
    float* out = (float*)d_out;
    unsigned short* ws = (unsigned short*)d_ws;   // needs 512 KB

    prep_kernel<<<128, 256, 0, stream>>>(gate_w, ws);
    router_kernel<<<TT / TB, 256, 0, stream>>>(hidden, gate_w, bias, ws, out);
}